// Round 10
// baseline (144.190 us; speedup 1.0000x reference)
//
#include <hip/hip_runtime.h>

#define HH 160
#define WW 160
#define DD 16
#define NG 8192
#define VOXEL 0.4f

// tiles: 20 x 20 x 4 (each 8x8x4 voxels) = 1600 tiles
#define TTX 20
#define TTY 20
#define TTZ 4
#define NTILES (TTX * TTY * TTZ)
#define CAP 128   // survivors per tile: lambda ~61, P(>128) ~ 8.6 sigma -> safe

// d_ws layout:
//   tileCnt  : NTILES int (6.4 KB)                 @ 0
//   tileData : NTILES * CAP * 12 float4 (39.3 MB)  @ 64 KB
// tileData record (12 float4 = 192 B, pack + feats INLINE -> voxelize
// inner-loop addresses are linear in n, never data-dependent):
//   [0] = (mu.x, mu.y, mu.z, opacity)
//   [1] = (3sx,  3sy,  3sz,  ci00)
//   [2] = (ci01, ci02, ci11, ci12)
//   [3] = (ci22, 0, 0, 0)
//   [4..11] = feats (32 floats)

__global__ __launch_bounds__(64) void gv_precompute_bin(
    const float* __restrict__ means, const float* __restrict__ opac,
    const float* __restrict__ scales, const float* __restrict__ rots,
    const float4* __restrict__ feats, int* __restrict__ tileCnt,
    float4* __restrict__ tileData) {
  int g = blockIdx.x * 64 + threadIdx.x;
  if (g >= NG) return;
  float qw = rots[g * 4 + 0], qx = rots[g * 4 + 1];
  float qy = rots[g * 4 + 2], qz = rots[g * 4 + 3];
  float inv = rsqrtf(qw * qw + qx * qx + qy * qy + qz * qz);
  qw *= inv; qx *= inv; qy *= inv; qz *= inv;
  float R[3][3];
  R[0][0] = 1.f - 2.f * (qy * qy + qz * qz);
  R[0][1] = 2.f * (qx * qy - qw * qz);
  R[0][2] = 2.f * (qx * qz + qw * qy);
  R[1][0] = 2.f * (qx * qy + qw * qz);
  R[1][1] = 1.f - 2.f * (qx * qx + qz * qz);
  R[1][2] = 2.f * (qy * qz - qw * qx);
  R[2][0] = 2.f * (qx * qz - qw * qy);
  R[2][1] = 2.f * (qy * qz + qw * qx);
  R[2][2] = 1.f - 2.f * (qx * qx + qy * qy);
  float sx = scales[g * 3 + 0], sy = scales[g * 3 + 1], sz = scales[g * 3 + 2];
  float s2[3] = {sx * sx, sy * sy, sz * sz};
  float is2[3] = {1.f / s2[0], 1.f / s2[1], 1.f / s2[2]};
  float cov00 = 0.f, cov11 = 0.f, cov22 = 0.f;
  float ci00 = 0.f, ci01 = 0.f, ci02 = 0.f, ci11 = 0.f, ci12 = 0.f, ci22 = 0.f;
#pragma unroll
  for (int c = 0; c < 3; c++) {
    cov00 += R[0][c] * R[0][c] * s2[c];
    cov11 += R[1][c] * R[1][c] * s2[c];
    cov22 += R[2][c] * R[2][c] * s2[c];
    ci00 += R[0][c] * R[0][c] * is2[c];
    ci01 += R[0][c] * R[1][c] * is2[c];
    ci02 += R[0][c] * R[2][c] * is2[c];
    ci11 += R[1][c] * R[1][c] * is2[c];
    ci12 += R[1][c] * R[2][c] * is2[c];
    ci22 += R[2][c] * R[2][c] * is2[c];
  }
  float mx = means[g * 3 + 0], my = means[g * 3 + 1], mz = means[g * 3 + 2];
  float bx = 3.f * sqrtf(cov00), by = 3.f * sqrtf(cov11), bz = 3.f * sqrtf(cov22);

  // voxel-center index ranges covered by bbox (with float-slop margin)
  const float eps = 1e-4f;
  int i0 = (int)ceilf((mx - bx + 32.f) * 2.5f - 0.5f - eps);
  int i1 = (int)floorf((mx + bx + 32.f) * 2.5f - 0.5f + eps);
  int j0 = (int)ceilf((my - by + 32.f) * 2.5f - 0.5f - eps);
  int j1 = (int)floorf((my + by + 32.f) * 2.5f - 0.5f + eps);
  int k0 = (int)ceilf((mz - bz + 1.f) * 2.5f - 0.5f - eps);
  int k1 = (int)floorf((mz + bz + 1.f) * 2.5f - 0.5f + eps);
  i0 = max(i0, 0); i1 = min(i1, HH - 1);
  j0 = max(j0, 0); j1 = min(j1, WW - 1);
  k0 = max(k0, 0); k1 = min(k1, DD - 1);
  if (i0 > i1 || j0 > j1 || k0 > k1) return;

  float4 p0 = make_float4(mx, my, mz, opac[g]);
  float4 p1 = make_float4(bx, by, bz, ci00);
  float4 p2 = make_float4(ci01, ci02, ci11, ci12);
  float4 p3 = make_float4(ci22, 0.f, 0.f, 0.f);
  const float4* __restrict__ fsrc = feats + (size_t)g * 8;
  float4 f0 = fsrc[0], f1 = fsrc[1], f2 = fsrc[2], f3 = fsrc[3];
  float4 f4 = fsrc[4], f5 = fsrc[5], f6 = fsrc[6], f7 = fsrc[7];

  int ti0 = i0 >> 3, ti1 = i1 >> 3;
  int tj0 = j0 >> 3, tj1 = j1 >> 3;
  int tk0 = k0 >> 2, tk1 = k1 >> 2;
  for (int ti = ti0; ti <= ti1; ti++)
    for (int tj = tj0; tj <= tj1; tj++)
      for (int tk = tk0; tk <= tk1; tk++) {
        int t = (ti * TTY + tj) * TTZ + tk;
        int pos = atomicAdd(&tileCnt[t], 1);
        if (pos < CAP) {
          float4* __restrict__ d = tileData + ((size_t)t * CAP + pos) * 12;
          d[0] = p0;  d[1] = p1;  d[2] = p2;  d[3] = p3;
          d[4] = f0;  d[5] = f1;  d[6] = f2;  d[7] = f3;
          d[8] = f4;  d[9] = f5;  d[10] = f6; d[11] = f7;
        }
      }
}

// Voxelize: NO pointer-chase. Gaussian records are inline in the per-tile
// list, so every inner-loop address is (tile base + n*192B) -- linear in
// the uniform loop counter, never dependent on a loaded value. A 2-gaussian
// step issues 6 independent s_load_dwordx16 and pays ONE lgkmcnt wait
// (~300 cyc) instead of two chained round-trips (~550). Loads are
// unconditional; FMA block is gated by __any to keep VALU work low.
__global__ __launch_bounds__(256) void gv_voxelize(
    const int* __restrict__ tileCnt, const float4* __restrict__ tileData,
    float4* __restrict__ out) {
  int tid = threadIdx.x;
  int dk = tid & 3, dj = (tid >> 2) & 7, di = tid >> 5;
  int tk = blockIdx.x, tj = blockIdx.y, ti = blockIdx.z;
  int i = ti * 8 + di, j = tj * 8 + dj, k = tk * 4 + dk;

  float px = (i + 0.5f) * VOXEL - 32.f;
  float py = (j + 0.5f) * VOXEL - 32.f;
  float pz = (k + 0.5f) * VOXEL - 1.f;

  int t = (ti * TTY + tj) * TTZ + tk;
  int cnt = tileCnt[t];
  cnt = min(cnt, CAP);
  const float4* __restrict__ gd = tileData + (size_t)t * CAP * 12;

  float4 acc[8];
#pragma unroll
  for (int f = 0; f < 8; f++) acc[f] = make_float4(0.f, 0.f, 0.f, 0.f);

  int n = 0;
  for (; n + 2 <= cnt; n += 2) {
    const float4* __restrict__ q0 = gd + (size_t)n * 12;
    const float4* __restrict__ q1 = q0 + 12;
    // 24 float4 loads, all from loop-linear uniform addresses
    float4 a0 = q0[0], b0 = q0[1], c0 = q0[2], d0 = q0[3];
    float4 e00 = q0[4], e01 = q0[5], e02 = q0[6], e03 = q0[7];
    float4 e04 = q0[8], e05 = q0[9], e06 = q0[10], e07 = q0[11];
    float4 a1 = q1[0], b1 = q1[1], c1 = q1[2], d1 = q1[3];
    float4 e10 = q1[4], e11 = q1[5], e12 = q1[6], e13 = q1[7];
    float4 e14 = q1[8], e15 = q1[9], e16 = q1[10], e17 = q1[11];

    float dx0 = px - a0.x, dy0 = py - a0.y, dz0 = pz - a0.z;
    float dx1 = px - a1.x, dy1 = py - a1.y, dz1 = pz - a1.z;
    bool in0 = (fabsf(dx0) <= b0.x) & (fabsf(dy0) <= b0.y) & (fabsf(dz0) <= b0.z);
    bool in1 = (fabsf(dx1) <= b1.x) & (fabsf(dy1) <= b1.y) & (fabsf(dz1) <= b1.z);

    if (__any(in0)) {
      float maha = b0.w * dx0 * dx0 + c0.z * dy0 * dy0 + d0.x * dz0 * dz0 +
                   2.f * (c0.x * dx0 * dy0 + c0.y * dx0 * dz0 + c0.w * dy0 * dz0);
      float wgt = in0 ? a0.w * __expf(-0.5f * maha) : 0.f;
      acc[0].x += wgt * e00.x; acc[0].y += wgt * e00.y; acc[0].z += wgt * e00.z; acc[0].w += wgt * e00.w;
      acc[1].x += wgt * e01.x; acc[1].y += wgt * e01.y; acc[1].z += wgt * e01.z; acc[1].w += wgt * e01.w;
      acc[2].x += wgt * e02.x; acc[2].y += wgt * e02.y; acc[2].z += wgt * e02.z; acc[2].w += wgt * e02.w;
      acc[3].x += wgt * e03.x; acc[3].y += wgt * e03.y; acc[3].z += wgt * e03.z; acc[3].w += wgt * e03.w;
      acc[4].x += wgt * e04.x; acc[4].y += wgt * e04.y; acc[4].z += wgt * e04.z; acc[4].w += wgt * e04.w;
      acc[5].x += wgt * e05.x; acc[5].y += wgt * e05.y; acc[5].z += wgt * e05.z; acc[5].w += wgt * e05.w;
      acc[6].x += wgt * e06.x; acc[6].y += wgt * e06.y; acc[6].z += wgt * e06.z; acc[6].w += wgt * e06.w;
      acc[7].x += wgt * e07.x; acc[7].y += wgt * e07.y; acc[7].z += wgt * e07.z; acc[7].w += wgt * e07.w;
    }
    if (__any(in1)) {
      float maha = b1.w * dx1 * dx1 + c1.z * dy1 * dy1 + d1.x * dz1 * dz1 +
                   2.f * (c1.x * dx1 * dy1 + c1.y * dx1 * dz1 + c1.w * dy1 * dz1);
      float wgt = in1 ? a1.w * __expf(-0.5f * maha) : 0.f;
      acc[0].x += wgt * e10.x; acc[0].y += wgt * e10.y; acc[0].z += wgt * e10.z; acc[0].w += wgt * e10.w;
      acc[1].x += wgt * e11.x; acc[1].y += wgt * e11.y; acc[1].z += wgt * e11.z; acc[1].w += wgt * e11.w;
      acc[2].x += wgt * e12.x; acc[2].y += wgt * e12.y; acc[2].z += wgt * e12.z; acc[2].w += wgt * e12.w;
      acc[3].x += wgt * e13.x; acc[3].y += wgt * e13.y; acc[3].z += wgt * e13.z; acc[3].w += wgt * e13.w;
      acc[4].x += wgt * e14.x; acc[4].y += wgt * e14.y; acc[4].z += wgt * e14.z; acc[4].w += wgt * e14.w;
      acc[5].x += wgt * e15.x; acc[5].y += wgt * e15.y; acc[5].z += wgt * e15.z; acc[5].w += wgt * e15.w;
      acc[6].x += wgt * e16.x; acc[6].y += wgt * e16.y; acc[6].z += wgt * e16.z; acc[6].w += wgt * e16.w;
      acc[7].x += wgt * e17.x; acc[7].y += wgt * e17.y; acc[7].z += wgt * e17.z; acc[7].w += wgt * e17.w;
    }
  }
  if (n < cnt) {
    const float4* __restrict__ q = gd + (size_t)n * 12;
    float4 pa = q[0], pb = q[1], pc = q[2], pd = q[3];
    float dx = px - pa.x, dy = py - pa.y, dz = pz - pa.z;
    bool in = (fabsf(dx) <= pb.x) & (fabsf(dy) <= pb.y) & (fabsf(dz) <= pb.z);
    if (__any(in)) {
      float maha = pb.w * dx * dx + pc.z * dy * dy + pd.x * dz * dz +
                   2.f * (pc.x * dx * dy + pc.y * dx * dz + pc.w * dy * dz);
      float wgt = in ? pa.w * __expf(-0.5f * maha) : 0.f;
#pragma unroll
      for (int f = 0; f < 8; f++) {
        float4 fv = q[4 + f];
        acc[f].x += wgt * fv.x;
        acc[f].y += wgt * fv.y;
        acc[f].z += wgt * fv.z;
        acc[f].w += wgt * fv.w;
      }
    }
  }

  size_t v = ((size_t)i * WW + j) * DD + k;
  float4* o = out + v * 8;
#pragma unroll
  for (int f = 0; f < 8; f++) o[f] = acc[f];
}

extern "C" void kernel_launch(void* const* d_in, const int* in_sizes, int n_in,
                              void* d_out, int out_size, void* d_ws, size_t ws_size,
                              hipStream_t stream) {
  const float* means  = (const float*)d_in[0];
  const float* opac   = (const float*)d_in[1];
  const float* scales = (const float*)d_in[2];
  const float* rots   = (const float*)d_in[3];
  const float4* feats = (const float4*)d_in[4];

  char* ws = (char*)d_ws;
  int* tileCnt     = (int*)ws;                        // 6.4 KB
  float4* tileData = (float4*)(ws + 64 * 1024);       // 39.3 MB

  hipMemsetAsync(tileCnt, 0, NTILES * sizeof(int), stream);
  gv_precompute_bin<<<128, 64, 0, stream>>>(means, opac, scales, rots,
                                            feats, tileCnt, tileData);
  dim3 grid(TTZ, TTY, TTX);
  gv_voxelize<<<grid, 256, 0, stream>>>(tileCnt, tileData, (float4*)d_out);
}

// Round 11
// 124.643 us; speedup vs baseline: 1.1568x; 1.1568x over previous
//
#include <hip/hip_runtime.h>

#define HH 160
#define WW 160
#define DD 16
#define NG 8192
#define VOXEL 0.4f

// tiles: 20 x 20 x 4 (each 8x8x4 voxels) = 1600 tiles
#define TTX 20
#define TTY 20
#define TTZ 4
#define NTILES (TTX * TTY * TTZ)
#define CAP 128   // survivors per tile: lambda ~61, P(>128) ~ 8.6 sigma -> safe

// d_ws layout:
//   tileCnt  : NTILES int (6.4 KB)                @ 0
//   tilePack : NTILES * CAP * 4 float4 (13.1 MB)  @ 64 KB
// tilePack record (4 float4 = 64 B, list-order inline; feats stay in the
// small L2-hot input buffer and are fetched by embedded index):
//   [0] = (mu.x, mu.y, mu.z, opacity)
//   [1] = (3sx,  3sy,  3sz,  ci00)
//   [2] = (ci01, ci02, ci11, ci12)
//   [3] = (ci22, as_float(g), 0, 0)

__global__ __launch_bounds__(64) void gv_precompute_bin(
    const float* __restrict__ means, const float* __restrict__ opac,
    const float* __restrict__ scales, const float* __restrict__ rots,
    int* __restrict__ tileCnt, float4* __restrict__ tilePack) {
  int g = blockIdx.x * 64 + threadIdx.x;
  if (g >= NG) return;
  float qw = rots[g * 4 + 0], qx = rots[g * 4 + 1];
  float qy = rots[g * 4 + 2], qz = rots[g * 4 + 3];
  float inv = rsqrtf(qw * qw + qx * qx + qy * qy + qz * qz);
  qw *= inv; qx *= inv; qy *= inv; qz *= inv;
  float R[3][3];
  R[0][0] = 1.f - 2.f * (qy * qy + qz * qz);
  R[0][1] = 2.f * (qx * qy - qw * qz);
  R[0][2] = 2.f * (qx * qz + qw * qy);
  R[1][0] = 2.f * (qx * qy + qw * qz);
  R[1][1] = 1.f - 2.f * (qx * qx + qz * qz);
  R[1][2] = 2.f * (qy * qz - qw * qx);
  R[2][0] = 2.f * (qx * qz - qw * qy);
  R[2][1] = 2.f * (qy * qz + qw * qx);
  R[2][2] = 1.f - 2.f * (qx * qx + qy * qy);
  float sx = scales[g * 3 + 0], sy = scales[g * 3 + 1], sz = scales[g * 3 + 2];
  float s2[3] = {sx * sx, sy * sy, sz * sz};
  float is2[3] = {1.f / s2[0], 1.f / s2[1], 1.f / s2[2]};
  float cov00 = 0.f, cov11 = 0.f, cov22 = 0.f;
  float ci00 = 0.f, ci01 = 0.f, ci02 = 0.f, ci11 = 0.f, ci12 = 0.f, ci22 = 0.f;
#pragma unroll
  for (int c = 0; c < 3; c++) {
    cov00 += R[0][c] * R[0][c] * s2[c];
    cov11 += R[1][c] * R[1][c] * s2[c];
    cov22 += R[2][c] * R[2][c] * s2[c];
    ci00 += R[0][c] * R[0][c] * is2[c];
    ci01 += R[0][c] * R[1][c] * is2[c];
    ci02 += R[0][c] * R[2][c] * is2[c];
    ci11 += R[1][c] * R[1][c] * is2[c];
    ci12 += R[1][c] * R[2][c] * is2[c];
    ci22 += R[2][c] * R[2][c] * is2[c];
  }
  float mx = means[g * 3 + 0], my = means[g * 3 + 1], mz = means[g * 3 + 2];
  float bx = 3.f * sqrtf(cov00), by = 3.f * sqrtf(cov11), bz = 3.f * sqrtf(cov22);

  // voxel-center index ranges covered by bbox (with float-slop margin)
  const float eps = 1e-4f;
  int i0 = (int)ceilf((mx - bx + 32.f) * 2.5f - 0.5f - eps);
  int i1 = (int)floorf((mx + bx + 32.f) * 2.5f - 0.5f + eps);
  int j0 = (int)ceilf((my - by + 32.f) * 2.5f - 0.5f - eps);
  int j1 = (int)floorf((my + by + 32.f) * 2.5f - 0.5f + eps);
  int k0 = (int)ceilf((mz - bz + 1.f) * 2.5f - 0.5f - eps);
  int k1 = (int)floorf((mz + bz + 1.f) * 2.5f - 0.5f + eps);
  i0 = max(i0, 0); i1 = min(i1, HH - 1);
  j0 = max(j0, 0); j1 = min(j1, WW - 1);
  k0 = max(k0, 0); k1 = min(k1, DD - 1);
  if (i0 > i1 || j0 > j1 || k0 > k1) return;

  float4 p0 = make_float4(mx, my, mz, opac[g]);
  float4 p1 = make_float4(bx, by, bz, ci00);
  float4 p2 = make_float4(ci01, ci02, ci11, ci12);
  float4 p3 = make_float4(ci22, __int_as_float(g), 0.f, 0.f);

  int ti0 = i0 >> 3, ti1 = i1 >> 3;
  int tj0 = j0 >> 3, tj1 = j1 >> 3;
  int tk0 = k0 >> 2, tk1 = k1 >> 2;
  for (int ti = ti0; ti <= ti1; ti++)
    for (int tj = tj0; tj <= tj1; tj++)
      for (int tk = tk0; tk <= tk1; tk++) {
        int t = (ti * TTY + tj) * TTZ + tk;
        int pos = atomicAdd(&tileCnt[t], 1);
        if (pos < CAP) {
          float4* __restrict__ d = tilePack + ((size_t)t * CAP + pos) * 4;
          d[0] = p0;  d[1] = p1;  d[2] = p2;  d[3] = p3;
        }
      }
}

// Voxelize: pack records staged in LDS once per block (coalesced vector
// loads, latency-free in parallel), so the inner-loop chain is
//   ds_read_b128 broadcast (~40cy) -> mask -> feats s_load from the
//   1 MB L2-HOT feats buffer (~250cy, pair-overlapped)
// instead of two chained scalar-cache-missing L2 round-trips (~550cy).
// Feats loads issue early (unconditional, pairwise); FMA blocks stay
// gated by __any.
__global__ __launch_bounds__(256) void gv_voxelize(
    const float4* __restrict__ feats, const int* __restrict__ tileCnt,
    const float4* __restrict__ tilePack, float4* __restrict__ out) {
  __shared__ float4 s_pack[CAP * 4];   // 8 KB

  int tid = threadIdx.x;
  int dk = tid & 3, dj = (tid >> 2) & 7, di = tid >> 5;
  int tk = blockIdx.x, tj = blockIdx.y, ti = blockIdx.z;
  int i = ti * 8 + di, j = tj * 8 + dj, k = tk * 4 + dk;

  float px = (i + 0.5f) * VOXEL - 32.f;
  float py = (j + 0.5f) * VOXEL - 32.f;
  float pz = (k + 0.5f) * VOXEL - 1.f;

  int t = (ti * TTY + tj) * TTZ + tk;
  int cnt = tileCnt[t];
  cnt = min(cnt, CAP);

  // stage pack records (coalesced, parallel)
  {
    const float4* __restrict__ src = tilePack + (size_t)t * CAP * 4;
    int tot = cnt * 4;
    for (int m = tid; m < tot; m += 256) s_pack[m] = src[m];
  }
  __syncthreads();

  float4 acc[8];
#pragma unroll
  for (int f = 0; f < 8; f++) acc[f] = make_float4(0.f, 0.f, 0.f, 0.f);

  int n = 0;
  for (; n + 2 <= cnt; n += 2) {
    float4 a0 = s_pack[n * 4 + 0], b0 = s_pack[n * 4 + 1];
    float4 c0 = s_pack[n * 4 + 2], d0 = s_pack[n * 4 + 3];
    float4 a1 = s_pack[n * 4 + 4], b1 = s_pack[n * 4 + 5];
    float4 c1 = s_pack[n * 4 + 6], d1 = s_pack[n * 4 + 7];

    int g0 = __builtin_amdgcn_readfirstlane(__float_as_int(d0.y));
    int g1 = __builtin_amdgcn_readfirstlane(__float_as_int(d1.y));
    const float4* __restrict__ fp0 = feats + (size_t)g0 * 8;
    const float4* __restrict__ fp1 = feats + (size_t)g1 * 8;
    // issue both feats load sets early (uniform -> s_load_dwordx16 pairs)
    float4 F0[8], F1[8];
#pragma unroll
    for (int f = 0; f < 8; f++) F0[f] = fp0[f];
#pragma unroll
    for (int f = 0; f < 8; f++) F1[f] = fp1[f];

    float dx0 = px - a0.x, dy0 = py - a0.y, dz0 = pz - a0.z;
    float dx1 = px - a1.x, dy1 = py - a1.y, dz1 = pz - a1.z;
    bool in0 = (fabsf(dx0) <= b0.x) & (fabsf(dy0) <= b0.y) & (fabsf(dz0) <= b0.z);
    bool in1 = (fabsf(dx1) <= b1.x) & (fabsf(dy1) <= b1.y) & (fabsf(dz1) <= b1.z);

    if (__any(in0)) {
      float maha = b0.w * dx0 * dx0 + c0.z * dy0 * dy0 + d0.x * dz0 * dz0 +
                   2.f * (c0.x * dx0 * dy0 + c0.y * dx0 * dz0 + c0.w * dy0 * dz0);
      float wgt = in0 ? a0.w * __expf(-0.5f * maha) : 0.f;
#pragma unroll
      for (int f = 0; f < 8; f++) {
        acc[f].x += wgt * F0[f].x;
        acc[f].y += wgt * F0[f].y;
        acc[f].z += wgt * F0[f].z;
        acc[f].w += wgt * F0[f].w;
      }
    }
    if (__any(in1)) {
      float maha = b1.w * dx1 * dx1 + c1.z * dy1 * dy1 + d1.x * dz1 * dz1 +
                   2.f * (c1.x * dx1 * dy1 + c1.y * dx1 * dz1 + c1.w * dy1 * dz1);
      float wgt = in1 ? a1.w * __expf(-0.5f * maha) : 0.f;
#pragma unroll
      for (int f = 0; f < 8; f++) {
        acc[f].x += wgt * F1[f].x;
        acc[f].y += wgt * F1[f].y;
        acc[f].z += wgt * F1[f].z;
        acc[f].w += wgt * F1[f].w;
      }
    }
  }
  if (n < cnt) {
    float4 pa = s_pack[n * 4 + 0], pb = s_pack[n * 4 + 1];
    float4 pc = s_pack[n * 4 + 2], pd = s_pack[n * 4 + 3];
    int gg = __builtin_amdgcn_readfirstlane(__float_as_int(pd.y));
    const float4* __restrict__ fp = feats + (size_t)gg * 8;
    float dx = px - pa.x, dy = py - pa.y, dz = pz - pa.z;
    bool in = (fabsf(dx) <= pb.x) & (fabsf(dy) <= pb.y) & (fabsf(dz) <= pb.z);
    if (__any(in)) {
      float maha = pb.w * dx * dx + pc.z * dy * dy + pd.x * dz * dz +
                   2.f * (pc.x * dx * dy + pc.y * dx * dz + pc.w * dy * dz);
      float wgt = in ? pa.w * __expf(-0.5f * maha) : 0.f;
#pragma unroll
      for (int f = 0; f < 8; f++) {
        float4 fv = fp[f];
        acc[f].x += wgt * fv.x;
        acc[f].y += wgt * fv.y;
        acc[f].z += wgt * fv.z;
        acc[f].w += wgt * fv.w;
      }
    }
  }

  size_t v = ((size_t)i * WW + j) * DD + k;
  float4* o = out + v * 8;
#pragma unroll
  for (int f = 0; f < 8; f++) o[f] = acc[f];
}

extern "C" void kernel_launch(void* const* d_in, const int* in_sizes, int n_in,
                              void* d_out, int out_size, void* d_ws, size_t ws_size,
                              hipStream_t stream) {
  const float* means  = (const float*)d_in[0];
  const float* opac   = (const float*)d_in[1];
  const float* scales = (const float*)d_in[2];
  const float* rots   = (const float*)d_in[3];
  const float4* feats = (const float4*)d_in[4];

  char* ws = (char*)d_ws;
  int* tileCnt     = (int*)ws;                        // 6.4 KB
  float4* tilePack = (float4*)(ws + 64 * 1024);       // 13.1 MB

  hipMemsetAsync(tileCnt, 0, NTILES * sizeof(int), stream);
  gv_precompute_bin<<<128, 64, 0, stream>>>(means, opac, scales, rots,
                                            tileCnt, tilePack);
  dim3 grid(TTZ, TTY, TTX);
  gv_voxelize<<<grid, 256, 0, stream>>>(feats, tileCnt, tilePack,
                                        (float4*)d_out);
}